// Round 9
// baseline (303.094 us; speedup 1.0000x reference)
//
#include <hip/hip_runtime.h>
#include <math.h>

#define NNODES 50000
#define NEDGES 800000
#define ETOT   850000      // NEDGES + NNODES self-loops
#define SLOPE  0.2f
#define BSLOTS 96          // bucket slots/node; P(Poisson(17) deg >= 96) < 1e-40

typedef unsigned short ushort_t;
typedef unsigned int   uint_t;
typedef __attribute__((ext_vector_type(8))) __bf16 bf16x8;
typedef __attribute__((ext_vector_type(4))) float  floatx4;

__device__ __forceinline__ float leaky(float v) { return fmaxf(v, SLOPE * v); }  // slope<1

__device__ __forceinline__ ushort_t f2bf(float f) {       // fp32 -> bf16 RNE
    uint_t u = __float_as_uint(f);
    uint_t r = (u + 0x7fffu + ((u >> 16) & 1u)) >> 16;
    return (ushort_t)r;
}
__device__ __forceinline__ float lof(uint_t u) { return __uint_as_float(u << 16); }
__device__ __forceinline__ float hif(uint_t u) { return __uint_as_float(u & 0xffff0000u); }

__device__ __forceinline__ float hsel(float4 v, int h) {  // v[h]
    float t0 = (h & 1) ? v.y : v.x;
    float t1 = (h & 1) ? v.w : v.z;
    return (h & 2) ? t1 : t0;
}

__device__ __forceinline__ int esrc(const int* ei, int e) { return e < NEDGES ? ei[e]          : e - NEDGES; }
__device__ __forceinline__ int edst(const int* ei, int e) { return e < NEDGES ? ei[NEDGES + e] : e - NEDGES; }

// ------- merged prep: bucketed CSR + W1->bf16 chunk conv + b1/W2 permute -------
// blocks [0,256): also convert their slice of W1; block 256: permute b1/W2.
__global__ void prep_k(const int* __restrict__ ei, int* __restrict__ cnt,
                       int* __restrict__ bkt,
                       const float* __restrict__ W1, ushort_t* __restrict__ W1c,
                       const float* __restrict__ b1, const float* __restrict__ W2,
                       float* __restrict__ b1p, float* __restrict__ W2p) {
    int bid = blockIdx.x, tid = threadIdx.x;
    if (bid < 256) {
        int i = bid * 256 + tid;              // 65536 elems, W1 row-major [k][n]
        int k = i >> 8, n = i & 255;
        W1c[(k >> 5) * 8192 + n * 32 + (k & 31)] = f2bf(W1[i]);
    } else if (bid == 256) {
        int chp = tid;                        // permuted channel: head*64 + c15*4 + tn
        int q = chp & 63, c = q >> 2, t = q & 3;
        int ch = (chp & 192) | (t * 16 + c);
        b1p[chp] = b1[ch];
        #pragma unroll
        for (int j = 0; j < 8; ++j) W2p[chp * 8 + j] = W2[ch * 8 + j];
    }
    int e = bid * 256 + tid;
    if (e < ETOT) {
        int d = edst(ei, e), s = esrc(ei, e);
        int pos = atomicAdd(&cnt[d], 1);
        if (pos < BSLOTS) bkt[d * BSLOTS + pos] = s;
    }
}

// ------- MFMA GEMM1 (bf16) + fused alpha1: h1b' = bf16(X@W1) permuted, as1/ad1 fp32 -------
__global__ __launch_bounds__(256) void gemm1_k(const float* __restrict__ X,
                                               const ushort_t* __restrict__ W1c,
                                               const float* __restrict__ att_s,
                                               const float* __restrict__ att_d,
                                               ushort_t* __restrict__ h1b,
                                               float* __restrict__ as1,
                                               float* __restrict__ ad1, int M) {
    __shared__ ushort_t Als[64 * 40];     // A tile [64][32] bf16, row pad to 40
    __shared__ ushort_t Bls[256 * 40];    // Bt tile [256 n][32 k] bf16, row pad to 40
    int tid = threadIdx.x;
    int row0 = blockIdx.x * 64;
    int wv = tid >> 6, lane = tid & 63, c15 = lane & 15, quad = lane >> 4;
    floatx4 acc[4][4] = {};               // [tm][tn]

    for (int kc = 0; kc < 8; ++kc) {
        __syncthreads();
        {
            int r = tid >> 3, c4 = tid & 7;
            #pragma unroll
            for (int p = 0; p < 2; ++p) {
                int rr = r + p * 32;
                int row = row0 + rr;
                float4 v = make_float4(0.f, 0.f, 0.f, 0.f);
                if (row < M) v = *(const float4*)&X[(size_t)row * 256 + kc * 32 + c4 * 4];
                uint2 pk;
                pk.x = (uint_t)f2bf(v.x) | ((uint_t)f2bf(v.y) << 16);
                pk.y = (uint_t)f2bf(v.z) | ((uint_t)f2bf(v.w) << 16);
                *(uint2*)&Als[rr * 40 + c4 * 4] = pk;
            }
        }
        {
            const uint4* srcp = (const uint4*)(W1c + kc * 8192);
            #pragma unroll
            for (int c = 0; c < 4; ++c) {
                int el = tid + c * 256;          // uint4 index, 1024 total
                uint4 v = srcp[el];
                int n = el >> 2, kk8 = (el & 3) * 8;
                *(uint4*)&Bls[n * 40 + kk8] = v;
            }
        }
        __syncthreads();
        uint4 af[4], bfr[4];
        #pragma unroll
        for (int t = 0; t < 4; ++t)
            af[t] = *(const uint4*)&Als[(t * 16 + c15) * 40 + quad * 8];
        #pragma unroll
        for (int t = 0; t < 4; ++t)
            bfr[t] = *(const uint4*)&Bls[(wv * 64 + t * 16 + c15) * 40 + quad * 8];
        #pragma unroll
        for (int tm = 0; tm < 4; ++tm)
            #pragma unroll
            for (int tn = 0; tn < 4; ++tn)
                acc[tm][tn] = __builtin_amdgcn_mfma_f32_16x16x32_bf16(
                    __builtin_bit_cast(bf16x8, af[tm]),
                    __builtin_bit_cast(bf16x8, bfr[tn]),
                    acc[tm][tn], 0, 0, 0);
    }

    // alpha partials on ORIGINAL channel indexing (heads unchanged by the permute)
    float asv[4], adv[4];
    #pragma unroll
    for (int tn = 0; tn < 4; ++tn) {
        asv[tn] = att_s[wv * 64 + tn * 16 + c15];
        adv[tn] = att_d[wv * 64 + tn * 16 + c15];
    }
    float ps[4][4], pd[4][4];
    #pragma unroll
    for (int tm = 0; tm < 4; ++tm)
        #pragma unroll
        for (int r = 0; r < 4; ++r) {
            float vs = 0.f, vd = 0.f;
            #pragma unroll
            for (int tn = 0; tn < 4; ++tn) {
                float a = acc[tm][tn][r];
                vs += a * asv[tn]; vd += a * adv[tn];
            }
            ps[tm][r] = vs; pd[tm][r] = vd;
        }
    // permuted stores: h1b'[row][wv*64 + c15*4 + tn] -> one uint2 (4 bf16) per (tm,r)
    #pragma unroll
    for (int tm = 0; tm < 4; ++tm) {
        #pragma unroll
        for (int r = 0; r < 4; ++r) {
            int row = row0 + tm * 16 + quad * 4 + r;
            if (row < M) {
                uint2 pk;
                pk.x = (uint_t)f2bf(acc[tm][0][r]) | ((uint_t)f2bf(acc[tm][1][r]) << 16);
                pk.y = (uint_t)f2bf(acc[tm][2][r]) | ((uint_t)f2bf(acc[tm][3][r]) << 16);
                *(uint2*)&h1b[(size_t)row * 256 + wv * 64 + c15 * 4] = pk;
            }
        }
    }
    #pragma unroll
    for (int off = 1; off < 16; off <<= 1)
        #pragma unroll
        for (int tm = 0; tm < 4; ++tm)
            #pragma unroll
            for (int r = 0; r < 4; ++r) {
                ps[tm][r] += __shfl_xor(ps[tm][r], off, 64);
                pd[tm][r] += __shfl_xor(pd[tm][r], off, 64);
            }
    if (c15 == 0) {
        #pragma unroll
        for (int tm = 0; tm < 4; ++tm)
            #pragma unroll
            for (int r = 0; r < 4; ++r) {
                int row = row0 + tm * 16 + quad * 4 + r;
                if (row < M) {
                    as1[row * 4 + wv] = ps[tm][r];
                    ad1[row * 4 + wv] = pd[tm][r];
                }
            }
    }
}

// ------- fused layer-1: TWO nodes per wave, 16 edges in flight per iteration -------
// Pad edges (e >= deg, e < nb16) carry weight 0 and load the node's own row —
// same-address, L1-hot, so the padding costs no HBM/L3 bandwidth.
__global__ __launch_bounds__(256) void f1_k(const int* __restrict__ cnt,
                                            const int* __restrict__ bkt,
                                            const float* __restrict__ as1,
                                            const float* __restrict__ ad1,
                                            const ushort_t* __restrict__ h1b,
                                            const float* __restrict__ b1p,
                                            const float* __restrict__ W2p,
                                            const float* __restrict__ a2sw,
                                            const float* __restrict__ a2dw,
                                            float* __restrict__ h2,
                                            float* __restrict__ a2s,
                                            float* __restrict__ a2d) {
    int wv = threadIdx.x >> 6;
    int lane = threadIdx.x & 63;
    int half = lane >> 5, l32 = lane & 31;
    int node = blockIdx.x * 8 + wv * 2 + half;
    int h = l32 >> 3;                     // head of this lane's 8 channels
    int deg = min(cnt[node], BSLOTS);
    const int* bp = bkt + (size_t)node * BSLOTS;
    float4 advec = *(const float4*)&ad1[(size_t)node * 4];
    __shared__ float wls[4][2][32][4];    // unnormalized exp weights per (edge, head)

    float acc[8] = {};
    float dn0, dn1, dn2, dn3;
    if (deg <= 32) {
        bool act = l32 < deg;
        int s_reg = node;                 // pad: self row (weight 0)
        if (act) s_reg = bp[l32];
        float4 av = *(const float4*)&as1[(size_t)s_reg * 4];
        float e0 = act ? __expf(leaky(av.x + advec.x)) : 0.f;
        float e1 = act ? __expf(leaky(av.y + advec.y)) : 0.f;
        float e2 = act ? __expf(leaky(av.z + advec.z)) : 0.f;
        float e3 = act ? __expf(leaky(av.w + advec.w)) : 0.f;
        *(float4*)&wls[wv][half][l32][0] = make_float4(e0, e1, e2, e3);
        dn0 = e0; dn1 = e1; dn2 = e2; dn3 = e3;
        #pragma unroll
        for (int off = 16; off; off >>= 1) {     // 32-lane reduce, stays in half
            dn0 += __shfl_xor(dn0, off, 64);
            dn1 += __shfl_xor(dn1, off, 64);
            dn2 += __shfl_xor(dn2, off, 64);
            dn3 += __shfl_xor(dn3, off, 64);
        }
        int nb = (deg + 15) & ~15;        // 16 or 32
        int sbase = half << 5;
        for (int base = 0; base < nb; base += 16) {
            #pragma unroll
            for (int u = 0; u < 16; ++u) {
                int e = base + u;
                int se = __shfl(s_reg, sbase + e, 64);
                float w = wls[wv][half][e][h];
                uint4 v = *(const uint4*)&h1b[(size_t)se * 256 + l32 * 8];
                acc[0] += w * lof(v.x); acc[1] += w * hif(v.x);
                acc[2] += w * lof(v.y); acc[3] += w * hif(v.y);
                acc[4] += w * lof(v.z); acc[5] += w * hif(v.z);
                acc[6] += w * lof(v.w); acc[7] += w * hif(v.w);
            }
        }
    } else {
        // fallback deg 33..96 — rare (P ~ 5e-4 per node)
        dn0 = dn1 = dn2 = dn3 = 0.f;
        for (int j = l32; j < deg; j += 32) {
            int s = bp[j];
            float4 av = *(const float4*)&as1[(size_t)s * 4];
            dn0 += __expf(leaky(av.x + advec.x));
            dn1 += __expf(leaky(av.y + advec.y));
            dn2 += __expf(leaky(av.z + advec.z));
            dn3 += __expf(leaky(av.w + advec.w));
        }
        #pragma unroll
        for (int off = 16; off; off >>= 1) {
            dn0 += __shfl_xor(dn0, off, 64);
            dn1 += __shfl_xor(dn1, off, 64);
            dn2 += __shfl_xor(dn2, off, 64);
            dn3 += __shfl_xor(dn3, off, 64);
        }
        float advh = hsel(advec, h);
        int cmax = deg - 1;
        for (int base = 0; base < deg; base += 8) {
            #pragma unroll
            for (int u = 0; u < 8; ++u) {
                int e = base + u;
                int ce = min(e, cmax);
                int se = bp[ce];
                float ash = as1[(size_t)se * 4 + h];
                float w = (e < deg) ? __expf(leaky(ash + advh)) : 0.f;
                uint4 v = *(const uint4*)&h1b[(size_t)se * 256 + l32 * 8];
                acc[0] += w * lof(v.x); acc[1] += w * hif(v.x);
                acc[2] += w * lof(v.y); acc[3] += w * hif(v.y);
                acc[4] += w * lof(v.z); acc[5] += w * hif(v.z);
                acc[6] += w * lof(v.w); acc[7] += w * hif(v.w);
            }
        }
    }
    float rdh = 1.f / hsel(make_float4(dn0, dn1, dn2, dn3), h);
    #pragma unroll
    for (int c = 0; c < 8; ++c) acc[c] *= rdh;

    // relu(acc + b1p) -> GEMM2 (256 -> 8, permuted rows) -> alpha2 dots
    int k0 = l32 * 8;
    float4 ba = *(const float4*)&b1p[k0];
    float4 bb = *(const float4*)&b1p[k0 + 4];
    float xv[8];
    xv[0] = fmaxf(acc[0] + ba.x, 0.f); xv[1] = fmaxf(acc[1] + ba.y, 0.f);
    xv[2] = fmaxf(acc[2] + ba.z, 0.f); xv[3] = fmaxf(acc[3] + ba.w, 0.f);
    xv[4] = fmaxf(acc[4] + bb.x, 0.f); xv[5] = fmaxf(acc[5] + bb.y, 0.f);
    xv[6] = fmaxf(acc[6] + bb.z, 0.f); xv[7] = fmaxf(acc[7] + bb.w, 0.f);
    float p[8] = {};
    #pragma unroll
    for (int q = 0; q < 8; ++q) {
        const float4* w2p = (const float4*)&W2p[(size_t)(k0 + q) * 8];
        float4 wa = w2p[0], wb = w2p[1];
        p[0] += xv[q] * wa.x; p[1] += xv[q] * wa.y; p[2] += xv[q] * wa.z; p[3] += xv[q] * wa.w;
        p[4] += xv[q] * wb.x; p[5] += xv[q] * wb.y; p[6] += xv[q] * wb.z; p[7] += xv[q] * wb.w;
    }
    #pragma unroll
    for (int off = 16; off; off >>= 1)
        #pragma unroll
        for (int c = 0; c < 8; ++c) p[c] += __shfl_xor(p[c], off, 64);
    if (l32 == 0) {
        *(float4*)&h2[(size_t)node * 8]     = make_float4(p[0], p[1], p[2], p[3]);
        *(float4*)&h2[(size_t)node * 8 + 4] = make_float4(p[4], p[5], p[6], p[7]);
        float vs = 0.f, vd = 0.f;
        #pragma unroll
        for (int c = 0; c < 8; ++c) { vs += p[c] * a2sw[c]; vd += p[c] * a2dw[c]; }
        a2s[node] = vs; a2d[node] = vd;
    }
}

// ------- fused layer-2: TWO nodes per wave, softmax-gather + bias + log_softmax -------
__global__ __launch_bounds__(256) void f2_k(const int* __restrict__ cnt,
                                            const int* __restrict__ bkt,
                                            const float* __restrict__ a2s,
                                            const float* __restrict__ a2d,
                                            const float* __restrict__ h2,
                                            const float* __restrict__ b2,
                                            float* __restrict__ out) {
    int wv = threadIdx.x >> 6;
    int lane = threadIdx.x & 63;
    int half = lane >> 5, l32 = lane & 31;
    int node = blockIdx.x * 8 + wv * 2 + half;
    int deg = min(cnt[node], BSLOTS);
    const int* bp = bkt + (size_t)node * BSLOTS;
    float adv = a2d[node];

    float acc = 0.f;
    float den;
    int c = l32 & 7, eg = l32 >> 3;        // 4 edges per pass, 8 channels each
    if (deg <= 32) {
        bool act = l32 < deg;
        int s_reg = node;
        if (act) s_reg = bp[l32];
        float ex = act ? __expf(leaky(a2s[s_reg] + adv)) : 0.f;
        den = ex;
        #pragma unroll
        for (int off = 16; off; off >>= 1) den += __shfl_xor(den, off, 64);
        int nb = (deg + 3) & ~3;
        int sbase = half << 5;
        for (int base = 0; base < nb; base += 4) {
            int e = base + eg;
            int se = __shfl(s_reg, sbase + e, 64);
            float w  = __shfl(ex,    sbase + e, 64);
            acc += w * h2[(size_t)se * 8 + c];
        }
    } else {
        den = 0.f;
        for (int j = l32; j < deg; j += 32) {
            int s = bp[j];
            den += __expf(leaky(a2s[s] + adv));
        }
        #pragma unroll
        for (int off = 16; off; off >>= 1) den += __shfl_xor(den, off, 64);
        int cmax = deg - 1;
        for (int base = 0; base < deg; base += 4) {
            int e = base + eg, ce = min(e, cmax);
            int se = bp[ce];
            float w = (e < deg) ? __expf(leaky(a2s[se] + adv)) : 0.f;
            acc += w * h2[(size_t)se * 8 + c];
        }
    }
    acc += __shfl_xor(acc, 8, 64);
    acc += __shfl_xor(acc, 16, 64);
    acc /= den;

    float v = acc + b2[c];
    float mx = v;
    #pragma unroll
    for (int off = 1; off < 8; off <<= 1) mx = fmaxf(mx, __shfl_xor(mx, off, 64));
    float ex2 = __expf(v - mx);
    float ss = ex2;
    #pragma unroll
    for (int off = 1; off < 8; off <<= 1) ss += __shfl_xor(ss, off, 64);
    if (l32 < 8) out[(size_t)node * 8 + c] = v - (mx + __logf(ss));
}

extern "C" void kernel_launch(void* const* d_in, const int* in_sizes, int n_in,
                              void* d_out, int out_size, void* d_ws, size_t ws_size,
                              hipStream_t stream) {
    const float* x    = (const float*)d_in[0];
    const int*   ei   = (const int*)  d_in[1];
    const float* W1   = (const float*)d_in[2];
    const float* a1sw = (const float*)d_in[3];
    const float* a1dw = (const float*)d_in[4];
    const float* b1   = (const float*)d_in[5];
    const float* W2   = (const float*)d_in[6];
    const float* a2sw = (const float*)d_in[7];
    const float* a2dw = (const float*)d_in[8];
    const float* b2   = (const float*)d_in[9];
    float* out = (float*)d_out;

    ushort_t* h1b = (ushort_t*)d_ws;          // 12,800,000 bf16 (permuted channels)
    ushort_t* W1c = h1b + 12800000;           //     65,536 bf16 (chunked W1)
    float* as1  = (float*)(W1c + 65536);      //    200,000 f (16B-aligned)
    float* ad1  = as1 + 200000;               //    200,000 f
    float* h2   = ad1 + 200000;               //    400,000 f
    float* a2s  = h2  + 400000;               //     50,000 f
    float* a2d  = a2s + 50000;                //     50,000 f
    float* b1p  = a2d + 50000;                //        256 f (permuted b1)
    float* W2p  = b1p + 256;                  //      2,048 f (permuted W2)
    int*   cnt  = (int*)(W2p + 2048);         //     50,000 i (zeroed by memset)
    int*   bkt  = cnt + 50000;                // 4,800,000 i (50000 * 96 slots)

    // ---- prep: zero cnt, then bucket CSR + W1 conv + b1/W2 permute (one kernel) ----
    hipMemsetAsync(cnt, 0, (size_t)50000 * sizeof(int), stream);
    prep_k<<<(ETOT + 255) / 256, 256, 0, stream>>>(ei, cnt, bkt, W1, W1c, b1, W2, b1p, W2p);

    // ---- layer 1 projection (MFMA bf16, fused alpha1, permuted store) ----
    gemm1_k<<<(NNODES + 63) / 64, 256, 0, stream>>>(x, W1c, a1sw, a1dw, h1b, as1, ad1, NNODES);

    // ---- fused layer-1 gather + GEMM2 + alpha2 (2 nodes per wave, 16-deep) ----
    f1_k<<<NNODES / 8, 256, 0, stream>>>(cnt, bkt, as1, ad1, h1b, b1p, W2p,
                                         a2sw, a2dw, h2, a2s, a2d);

    // ---- fused layer-2 gather + log_softmax (2 nodes per wave) ----
    f2_k<<<NNODES / 8, 256, 0, stream>>>(cnt, bkt, a2s, a2d, h2, b2, out);
}

// Round 11
// 286.077 us; speedup vs baseline: 1.0595x; 1.0595x over previous
//
#include <hip/hip_runtime.h>
#include <math.h>

#define NNODES 50000
#define NEDGES 800000
#define ETOT   850000      // NEDGES + NNODES self-loops
#define SLOPE  0.2f
#define BSLOTS 96          // bucket slots/node; P(Poisson(17) deg >= 96) < 1e-40
#define NTILE  782         // ceil(NNODES/64) gemm1 tiles
#define BBLK   518         // bucket blocks appended after the gemm tiles

typedef unsigned short ushort_t;
typedef unsigned int   uint_t;
typedef __attribute__((ext_vector_type(8))) __bf16 bf16x8;
typedef __attribute__((ext_vector_type(4))) float  floatx4;

__device__ __forceinline__ float leaky(float v) { return fmaxf(v, SLOPE * v); }  // slope<1

__device__ __forceinline__ ushort_t f2bf(float f) {       // fp32 -> bf16 RNE
    uint_t u = __float_as_uint(f);
    uint_t r = (u + 0x7fffu + ((u >> 16) & 1u)) >> 16;
    return (ushort_t)r;
}
__device__ __forceinline__ float lof(uint_t u) { return __uint_as_float(u << 16); }
__device__ __forceinline__ float hif(uint_t u) { return __uint_as_float(u & 0xffff0000u); }

__device__ __forceinline__ float hsel(float4 v, int h) {  // v[h]
    float t0 = (h & 1) ? v.y : v.x;
    float t1 = (h & 1) ? v.w : v.z;
    return (h & 2) ? t1 : t0;
}

__device__ __forceinline__ int esrc(const int* ei, int e) { return e < NEDGES ? ei[e]          : e - NEDGES; }
__device__ __forceinline__ int edst(const int* ei, int e) { return e < NEDGES ? ei[NEDGES + e] : e - NEDGES; }

// ------- prep: W1->bf16 chunk conv + b1/W2 permute + cnt zero (one kernel) -------
__global__ void prep_k(const float* __restrict__ W1, ushort_t* __restrict__ W1c,
                       const float* __restrict__ b1, const float* __restrict__ W2,
                       float* __restrict__ b1p, float* __restrict__ W2p,
                       int* __restrict__ cnt) {
    int bid = blockIdx.x, tid = threadIdx.x;
    int gtid = bid * 256 + tid;
    if (bid < 256) {                          // W1 row-major [k][n] -> W1c[kc][n][kk]
        int k = gtid >> 8, n = gtid & 255;
        W1c[(k >> 5) * 8192 + n * 32 + (k & 31)] = f2bf(W1[gtid]);
    } else if (bid == 256) {                  // permuted channel: head*64 + c15*4 + tn
        int chp = tid;
        int q = chp & 63, cc = q >> 2, t = q & 3;
        int ch = (chp & 192) | (t * 16 + cc);
        b1p[chp] = b1[ch];
        #pragma unroll
        for (int j = 0; j < 8; ++j) W2p[chp * 8 + j] = W2[ch * 8 + j];
    }
    if (gtid < NNODES) cnt[gtid] = 0;
}

// ------- fused gemm1 || bucket: blocks [0,NTILE) do MFMA tiles, rest bucket edges -------
// The two halves touch disjoint data (x/W1c vs ei) and only f1 consumes both ->
// no intra-kernel ordering needed; scheduler overlaps MFMA-heavy and atomic-heavy blocks.
__global__ __launch_bounds__(256) void gb_k(const float* __restrict__ X,
                                            const ushort_t* __restrict__ W1c,
                                            const float* __restrict__ att_s,
                                            const float* __restrict__ att_d,
                                            ushort_t* __restrict__ h1b,
                                            float* __restrict__ as1,
                                            float* __restrict__ ad1,
                                            const int* __restrict__ ei,
                                            int* __restrict__ cnt,
                                            int* __restrict__ bkt) {
    __shared__ ushort_t Als[64 * 40];     // A tile [64][32] bf16, row pad to 40
    __shared__ ushort_t Bls[256 * 40];    // Bt tile [256 n][32 k] bf16, row pad to 40
    int tid = threadIdx.x;

    if (blockIdx.x >= NTILE) {
        // -------- bucketed CSR over the edge list (+ implicit self-loops) --------
        for (int e = (blockIdx.x - NTILE) * 256 + tid; e < ETOT; e += BBLK * 256) {
            int d = edst(ei, e), s = esrc(ei, e);
            int pos = atomicAdd(&cnt[d], 1);
            if (pos < BSLOTS) bkt[d * BSLOTS + pos] = s;
        }
        return;
    }

    // -------- one 64-row gemm tile --------
    int row0 = blockIdx.x * 64;
    int wv = tid >> 6, lane = tid & 63, c15 = lane & 15, quad = lane >> 4;
    floatx4 acc[4][4] = {};               // [tm][tn]

    for (int kc = 0; kc < 8; ++kc) {
        __syncthreads();
        {
            int r = tid >> 3, c4 = tid & 7;
            #pragma unroll
            for (int p = 0; p < 2; ++p) {
                int rr = r + p * 32;
                int row = row0 + rr;
                float4 v = make_float4(0.f, 0.f, 0.f, 0.f);
                if (row < NNODES) v = *(const float4*)&X[(size_t)row * 256 + kc * 32 + c4 * 4];
                uint2 pk;
                pk.x = (uint_t)f2bf(v.x) | ((uint_t)f2bf(v.y) << 16);
                pk.y = (uint_t)f2bf(v.z) | ((uint_t)f2bf(v.w) << 16);
                *(uint2*)&Als[rr * 40 + c4 * 4] = pk;
            }
        }
        {
            const uint4* srcp = (const uint4*)(W1c + kc * 8192);
            #pragma unroll
            for (int c = 0; c < 4; ++c) {
                int el = tid + c * 256;          // uint4 index, 1024 total
                uint4 v = srcp[el];
                int n = el >> 2, kk8 = (el & 3) * 8;
                *(uint4*)&Bls[n * 40 + kk8] = v;
            }
        }
        __syncthreads();
        uint4 af[4], bfr[4];
        #pragma unroll
        for (int t = 0; t < 4; ++t)
            af[t] = *(const uint4*)&Als[(t * 16 + c15) * 40 + quad * 8];
        #pragma unroll
        for (int t = 0; t < 4; ++t)
            bfr[t] = *(const uint4*)&Bls[(wv * 64 + t * 16 + c15) * 40 + quad * 8];
        #pragma unroll
        for (int tm = 0; tm < 4; ++tm)
            #pragma unroll
            for (int tn = 0; tn < 4; ++tn)
                acc[tm][tn] = __builtin_amdgcn_mfma_f32_16x16x32_bf16(
                    __builtin_bit_cast(bf16x8, af[tm]),
                    __builtin_bit_cast(bf16x8, bfr[tn]),
                    acc[tm][tn], 0, 0, 0);
    }

    // alpha partials on ORIGINAL channel indexing (heads unchanged by the permute)
    float asv[4], adv[4];
    #pragma unroll
    for (int tn = 0; tn < 4; ++tn) {
        asv[tn] = att_s[wv * 64 + tn * 16 + c15];
        adv[tn] = att_d[wv * 64 + tn * 16 + c15];
    }
    float ps[4][4], pd[4][4];
    #pragma unroll
    for (int tm = 0; tm < 4; ++tm)
        #pragma unroll
        for (int r = 0; r < 4; ++r) {
            float vs = 0.f, vd = 0.f;
            #pragma unroll
            for (int tn = 0; tn < 4; ++tn) {
                float a = acc[tm][tn][r];
                vs += a * asv[tn]; vd += a * adv[tn];
            }
            ps[tm][r] = vs; pd[tm][r] = vd;
        }
    // permuted stores: h1b'[row][wv*64 + c15*4 + tn] -> one uint2 (4 bf16) per (tm,r)
    #pragma unroll
    for (int tm = 0; tm < 4; ++tm) {
        #pragma unroll
        for (int r = 0; r < 4; ++r) {
            int row = row0 + tm * 16 + quad * 4 + r;
            if (row < NNODES) {
                uint2 pk;
                pk.x = (uint_t)f2bf(acc[tm][0][r]) | ((uint_t)f2bf(acc[tm][1][r]) << 16);
                pk.y = (uint_t)f2bf(acc[tm][2][r]) | ((uint_t)f2bf(acc[tm][3][r]) << 16);
                *(uint2*)&h1b[(size_t)row * 256 + wv * 64 + c15 * 4] = pk;
            }
        }
    }
    #pragma unroll
    for (int off = 1; off < 16; off <<= 1)
        #pragma unroll
        for (int tm = 0; tm < 4; ++tm)
            #pragma unroll
            for (int r = 0; r < 4; ++r) {
                ps[tm][r] += __shfl_xor(ps[tm][r], off, 64);
                pd[tm][r] += __shfl_xor(pd[tm][r], off, 64);
            }
    if (c15 == 0) {
        #pragma unroll
        for (int tm = 0; tm < 4; ++tm)
            #pragma unroll
            for (int r = 0; r < 4; ++r) {
                int row = row0 + tm * 16 + quad * 4 + r;
                if (row < NNODES) {
                    as1[row * 4 + wv] = ps[tm][r];
                    ad1[row * 4 + wv] = pd[tm][r];
                }
            }
    }
}

// ------- fused layer-1: TWO nodes per wave, 8-deep reg-shuffle gather (r8 verbatim) -------
__global__ __launch_bounds__(256) void f1_k(const int* __restrict__ cnt,
                                            const int* __restrict__ bkt,
                                            const float* __restrict__ as1,
                                            const float* __restrict__ ad1,
                                            const ushort_t* __restrict__ h1b,
                                            const float* __restrict__ b1p,
                                            const float* __restrict__ W2p,
                                            const float* __restrict__ a2sw,
                                            const float* __restrict__ a2dw,
                                            float* __restrict__ h2,
                                            float* __restrict__ a2s,
                                            float* __restrict__ a2d) {
    int wv = threadIdx.x >> 6;
    int lane = threadIdx.x & 63;
    int half = lane >> 5, l32 = lane & 31;
    int node = blockIdx.x * 8 + wv * 2 + half;
    int h = l32 >> 3;                     // head of this lane's 8 channels
    int deg = min(cnt[node], BSLOTS);
    const int* bp = bkt + (size_t)node * BSLOTS;
    float4 advec = *(const float4*)&ad1[(size_t)node * 4];
    __shared__ float wls[4][2][32][4];    // unnormalized exp weights per (edge, head)

    float acc[8] = {};
    float dn0, dn1, dn2, dn3;
    if (deg <= 32) {
        bool act = l32 < deg;
        int s_reg = node;                 // pad: self row (weight 0)
        if (act) s_reg = bp[l32];
        float4 av = *(const float4*)&as1[(size_t)s_reg * 4];
        float e0 = act ? __expf(leaky(av.x + advec.x)) : 0.f;
        float e1 = act ? __expf(leaky(av.y + advec.y)) : 0.f;
        float e2 = act ? __expf(leaky(av.z + advec.z)) : 0.f;
        float e3 = act ? __expf(leaky(av.w + advec.w)) : 0.f;
        *(float4*)&wls[wv][half][l32][0] = make_float4(e0, e1, e2, e3);
        dn0 = e0; dn1 = e1; dn2 = e2; dn3 = e3;
        #pragma unroll
        for (int off = 16; off; off >>= 1) {     // 32-lane reduce, stays in half
            dn0 += __shfl_xor(dn0, off, 64);
            dn1 += __shfl_xor(dn1, off, 64);
            dn2 += __shfl_xor(dn2, off, 64);
            dn3 += __shfl_xor(dn3, off, 64);
        }
        int nb = (deg + 7) & ~7;          // 8-deep batches
        int sbase = half << 5;
        for (int base = 0; base < nb; base += 8) {
            #pragma unroll
            for (int u = 0; u < 8; ++u) {
                int e = base + u;
                int se = __shfl(s_reg, sbase + e, 64);
                float w = wls[wv][half][e][h];
                uint4 v = *(const uint4*)&h1b[(size_t)se * 256 + l32 * 8];
                acc[0] += w * lof(v.x); acc[1] += w * hif(v.x);
                acc[2] += w * lof(v.y); acc[3] += w * hif(v.y);
                acc[4] += w * lof(v.z); acc[5] += w * hif(v.z);
                acc[6] += w * lof(v.w); acc[7] += w * hif(v.w);
            }
        }
    } else {
        // fallback deg 33..96 — rare (P ~ 5e-4 per node)
        dn0 = dn1 = dn2 = dn3 = 0.f;
        for (int j = l32; j < deg; j += 32) {
            int s = bp[j];
            float4 av = *(const float4*)&as1[(size_t)s * 4];
            dn0 += __expf(leaky(av.x + advec.x));
            dn1 += __expf(leaky(av.y + advec.y));
            dn2 += __expf(leaky(av.z + advec.z));
            dn3 += __expf(leaky(av.w + advec.w));
        }
        #pragma unroll
        for (int off = 16; off; off >>= 1) {
            dn0 += __shfl_xor(dn0, off, 64);
            dn1 += __shfl_xor(dn1, off, 64);
            dn2 += __shfl_xor(dn2, off, 64);
            dn3 += __shfl_xor(dn3, off, 64);
        }
        float advh = hsel(advec, h);
        int cmax = deg - 1;
        for (int base = 0; base < deg; base += 8) {
            #pragma unroll
            for (int u = 0; u < 8; ++u) {
                int e = base + u;
                int ce = min(e, cmax);
                int se = bp[ce];
                float ash = as1[(size_t)se * 4 + h];
                float w = (e < deg) ? __expf(leaky(ash + advh)) : 0.f;
                uint4 v = *(const uint4*)&h1b[(size_t)se * 256 + l32 * 8];
                acc[0] += w * lof(v.x); acc[1] += w * hif(v.x);
                acc[2] += w * lof(v.y); acc[3] += w * hif(v.y);
                acc[4] += w * lof(v.z); acc[5] += w * hif(v.z);
                acc[6] += w * lof(v.w); acc[7] += w * hif(v.w);
            }
        }
    }
    float rdh = 1.f / hsel(make_float4(dn0, dn1, dn2, dn3), h);
    #pragma unroll
    for (int c = 0; c < 8; ++c) acc[c] *= rdh;

    // relu(acc + b1p) -> GEMM2 (256 -> 8, permuted rows) -> alpha2 dots
    int k0 = l32 * 8;
    float4 ba = *(const float4*)&b1p[k0];
    float4 bb = *(const float4*)&b1p[k0 + 4];
    float xv[8];
    xv[0] = fmaxf(acc[0] + ba.x, 0.f); xv[1] = fmaxf(acc[1] + ba.y, 0.f);
    xv[2] = fmaxf(acc[2] + ba.z, 0.f); xv[3] = fmaxf(acc[3] + ba.w, 0.f);
    xv[4] = fmaxf(acc[4] + bb.x, 0.f); xv[5] = fmaxf(acc[5] + bb.y, 0.f);
    xv[6] = fmaxf(acc[6] + bb.z, 0.f); xv[7] = fmaxf(acc[7] + bb.w, 0.f);
    float p[8] = {};
    #pragma unroll
    for (int q = 0; q < 8; ++q) {
        const float4* w2p = (const float4*)&W2p[(size_t)(k0 + q) * 8];
        float4 wa = w2p[0], wb = w2p[1];
        p[0] += xv[q] * wa.x; p[1] += xv[q] * wa.y; p[2] += xv[q] * wa.z; p[3] += xv[q] * wa.w;
        p[4] += xv[q] * wb.x; p[5] += xv[q] * wb.y; p[6] += xv[q] * wb.z; p[7] += xv[q] * wb.w;
    }
    #pragma unroll
    for (int off = 16; off; off >>= 1)
        #pragma unroll
        for (int c = 0; c < 8; ++c) p[c] += __shfl_xor(p[c], off, 64);
    if (l32 == 0) {
        *(float4*)&h2[(size_t)node * 8]     = make_float4(p[0], p[1], p[2], p[3]);
        *(float4*)&h2[(size_t)node * 8 + 4] = make_float4(p[4], p[5], p[6], p[7]);
        float vs = 0.f, vd = 0.f;
        #pragma unroll
        for (int c = 0; c < 8; ++c) { vs += p[c] * a2sw[c]; vd += p[c] * a2dw[c]; }
        a2s[node] = vs; a2d[node] = vd;
    }
}

// ------- fused layer-2: TWO nodes per wave, softmax-gather + bias + log_softmax -------
__global__ __launch_bounds__(256) void f2_k(const int* __restrict__ cnt,
                                            const int* __restrict__ bkt,
                                            const float* __restrict__ a2s,
                                            const float* __restrict__ a2d,
                                            const float* __restrict__ h2,
                                            const float* __restrict__ b2,
                                            float* __restrict__ out) {
    int wv = threadIdx.x >> 6;
    int lane = threadIdx.x & 63;
    int half = lane >> 5, l32 = lane & 31;
    int node = blockIdx.x * 8 + wv * 2 + half;
    int deg = min(cnt[node], BSLOTS);
    const int* bp = bkt + (size_t)node * BSLOTS;
    float adv = a2d[node];

    float acc = 0.f;
    float den;
    int c = l32 & 7, eg = l32 >> 3;        // 4 edges per pass, 8 channels each
    if (deg <= 32) {
        bool act = l32 < deg;
        int s_reg = node;
        if (act) s_reg = bp[l32];
        float ex = act ? __expf(leaky(a2s[s_reg] + adv)) : 0.f;
        den = ex;
        #pragma unroll
        for (int off = 16; off; off >>= 1) den += __shfl_xor(den, off, 64);
        int nb = (deg + 3) & ~3;
        int sbase = half << 5;
        for (int base = 0; base < nb; base += 4) {
            int e = base + eg;
            int se = __shfl(s_reg, sbase + e, 64);
            float w  = __shfl(ex,    sbase + e, 64);
            acc += w * h2[(size_t)se * 8 + c];
        }
    } else {
        den = 0.f;
        for (int j = l32; j < deg; j += 32) {
            int s = bp[j];
            den += __expf(leaky(a2s[s] + adv));
        }
        #pragma unroll
        for (int off = 16; off; off >>= 1) den += __shfl_xor(den, off, 64);
        int cmax = deg - 1;
        for (int base = 0; base < deg; base += 4) {
            int e = base + eg, ce = min(e, cmax);
            int se = bp[ce];
            float w = (e < deg) ? __expf(leaky(a2s[se] + adv)) : 0.f;
            acc += w * h2[(size_t)se * 8 + c];
        }
    }
    acc += __shfl_xor(acc, 8, 64);
    acc += __shfl_xor(acc, 16, 64);
    acc /= den;

    float v = acc + b2[c];
    float mx = v;
    #pragma unroll
    for (int off = 1; off < 8; off <<= 1) mx = fmaxf(mx, __shfl_xor(mx, off, 64));
    float ex2 = __expf(v - mx);
    float ss = ex2;
    #pragma unroll
    for (int off = 1; off < 8; off <<= 1) ss += __shfl_xor(ss, off, 64);
    if (l32 < 8) out[(size_t)node * 8 + c] = v - (mx + __logf(ss));
}

extern "C" void kernel_launch(void* const* d_in, const int* in_sizes, int n_in,
                              void* d_out, int out_size, void* d_ws, size_t ws_size,
                              hipStream_t stream) {
    const float* x    = (const float*)d_in[0];
    const int*   ei   = (const int*)  d_in[1];
    const float* W1   = (const float*)d_in[2];
    const float* a1sw = (const float*)d_in[3];
    const float* a1dw = (const float*)d_in[4];
    const float* b1   = (const float*)d_in[5];
    const float* W2   = (const float*)d_in[6];
    const float* a2sw = (const float*)d_in[7];
    const float* a2dw = (const float*)d_in[8];
    const float* b2   = (const float*)d_in[9];
    float* out = (float*)d_out;

    ushort_t* h1b = (ushort_t*)d_ws;          // 12,800,000 bf16 (permuted channels)
    ushort_t* W1c = h1b + 12800000;           //     65,536 bf16 (chunked W1)
    float* as1  = (float*)(W1c + 65536);      //    200,000 f (16B-aligned)
    float* ad1  = as1 + 200000;               //    200,000 f
    float* h2   = ad1 + 200000;               //    400,000 f
    float* a2s  = h2  + 400000;               //     50,000 f
    float* a2d  = a2s + 50000;                //     50,000 f
    float* b1p  = a2d + 50000;                //        256 f (permuted b1)
    float* W2p  = b1p + 256;                  //      2,048 f (permuted W2)
    int*   cnt  = (int*)(W2p + 2048);         //     50,000 i (zeroed in prep_k)
    int*   bkt  = cnt + 50000;                // 4,800,000 i (50000 * 96 slots)

    // ---- prep: W1 conv + b1/W2 permute + cnt zero ----
    prep_k<<<257, 256, 0, stream>>>(W1, W1c, b1, W2, b1p, W2p, cnt);

    // ---- gemm1 (MFMA bf16, fused alpha1, permuted store) || bucketed CSR ----
    gb_k<<<NTILE + BBLK, 256, 0, stream>>>(x, W1c, a1sw, a1dw, h1b, as1, ad1,
                                           ei, cnt, bkt);

    // ---- fused layer-1 gather + GEMM2 + alpha2 (2 nodes per wave, 8-deep) ----
    f1_k<<<NNODES / 8, 256, 0, stream>>>(cnt, bkt, as1, ad1, h1b, b1p, W2p,
                                         a2sw, a2dw, h2, a2s, a2d);

    // ---- fused layer-2 gather + log_softmax (2 nodes per wave) ----
    f2_k<<<NNODES / 8, 256, 0, stream>>>(cnt, bkt, a2s, a2d, h2, b2, out);
}

// Round 12
// 281.420 us; speedup vs baseline: 1.0770x; 1.0165x over previous
//
#include <hip/hip_runtime.h>
#include <math.h>

#define NNODES 50000
#define NEDGES 800000
#define ETOT   850000      // NEDGES + NNODES self-loops
#define SLOPE  0.2f
#define BSLOTS 96          // bucket slots/node; P(Poisson(17) deg >= 96) < 1e-40
#define CPAD   16          // cnt stride: one counter per 64B line (atomic false-sharing fix)
#define NTILE  782         // ceil(NNODES/64) gemm1 tiles
#define BBLK   518         // bucket blocks appended after the gemm tiles

typedef unsigned short ushort_t;
typedef unsigned int   uint_t;
typedef __attribute__((ext_vector_type(8))) __bf16 bf16x8;
typedef __attribute__((ext_vector_type(4))) float  floatx4;

__device__ __forceinline__ float leaky(float v) { return fmaxf(v, SLOPE * v); }  // slope<1

__device__ __forceinline__ ushort_t f2bf(float f) {       // fp32 -> bf16 RNE
    uint_t u = __float_as_uint(f);
    uint_t r = (u + 0x7fffu + ((u >> 16) & 1u)) >> 16;
    return (ushort_t)r;
}
__device__ __forceinline__ float lof(uint_t u) { return __uint_as_float(u << 16); }
__device__ __forceinline__ float hif(uint_t u) { return __uint_as_float(u & 0xffff0000u); }

__device__ __forceinline__ float hsel(float4 v, int h) {  // v[h]
    float t0 = (h & 1) ? v.y : v.x;
    float t1 = (h & 1) ? v.w : v.z;
    return (h & 2) ? t1 : t0;
}

__device__ __forceinline__ int esrc(const int* ei, int e) { return e < NEDGES ? ei[e]          : e - NEDGES; }
__device__ __forceinline__ int edst(const int* ei, int e) { return e < NEDGES ? ei[NEDGES + e] : e - NEDGES; }

// ------- prep: W1->bf16 chunk conv + b1/W2 permute + padded-cnt zero (one kernel) -------
__global__ void prep_k(const float* __restrict__ W1, ushort_t* __restrict__ W1c,
                       const float* __restrict__ b1, const float* __restrict__ W2,
                       float* __restrict__ b1p, float* __restrict__ W2p,
                       int* __restrict__ cnt) {
    int bid = blockIdx.x, tid = threadIdx.x;
    int gtid = bid * 256 + tid;
    if (bid < 256) {                          // W1 row-major [k][n] -> W1c[kc][n][kk]
        int k = gtid >> 8, n = gtid & 255;
        W1c[(k >> 5) * 8192 + n * 32 + (k & 31)] = f2bf(W1[gtid]);
    } else if (bid == 256) {                  // permuted channel: head*64 + c15*4 + tn
        int chp = tid;
        int q = chp & 63, cc = q >> 2, t = q & 3;
        int ch = (chp & 192) | (t * 16 + cc);
        b1p[chp] = b1[ch];
        #pragma unroll
        for (int j = 0; j < 8; ++j) W2p[chp * 8 + j] = W2[ch * 8 + j];
    }
    for (int i = gtid; i < NNODES * CPAD; i += 257 * 256) cnt[i] = 0;
}

// ------- fused gemm1 || bucket: blocks [0,NTILE) do MFMA tiles, rest bucket edges -------
__global__ __launch_bounds__(256) void gb_k(const float* __restrict__ X,
                                            const ushort_t* __restrict__ W1c,
                                            const float* __restrict__ att_s,
                                            const float* __restrict__ att_d,
                                            ushort_t* __restrict__ h1b,
                                            float* __restrict__ as1,
                                            float* __restrict__ ad1,
                                            const int* __restrict__ ei,
                                            int* __restrict__ cnt,
                                            int* __restrict__ bkt) {
    __shared__ ushort_t Als[64 * 40];     // A tile [64][32] bf16, row pad to 40
    __shared__ ushort_t Bls[256 * 40];    // Bt tile [256 n][32 k] bf16, row pad to 40
    int tid = threadIdx.x;

    if (blockIdx.x >= NTILE) {
        // -------- bucketed CSR over the edge list (+ implicit self-loops) --------
        for (int e = (blockIdx.x - NTILE) * 256 + tid; e < ETOT; e += BBLK * 256) {
            int d = edst(ei, e), s = esrc(ei, e);
            int pos = atomicAdd(&cnt[d * CPAD], 1);
            if (pos < BSLOTS) bkt[d * BSLOTS + pos] = s;
        }
        return;
    }

    // -------- one 64-row gemm tile --------
    int row0 = blockIdx.x * 64;
    int wv = tid >> 6, lane = tid & 63, c15 = lane & 15, quad = lane >> 4;
    floatx4 acc[4][4] = {};               // [tm][tn]

    for (int kc = 0; kc < 8; ++kc) {
        __syncthreads();
        {
            int r = tid >> 3, c4 = tid & 7;
            #pragma unroll
            for (int p = 0; p < 2; ++p) {
                int rr = r + p * 32;
                int row = row0 + rr;
                float4 v = make_float4(0.f, 0.f, 0.f, 0.f);
                if (row < NNODES) v = *(const float4*)&X[(size_t)row * 256 + kc * 32 + c4 * 4];
                uint2 pk;
                pk.x = (uint_t)f2bf(v.x) | ((uint_t)f2bf(v.y) << 16);
                pk.y = (uint_t)f2bf(v.z) | ((uint_t)f2bf(v.w) << 16);
                *(uint2*)&Als[rr * 40 + c4 * 4] = pk;
            }
        }
        {
            const uint4* srcp = (const uint4*)(W1c + kc * 8192);
            #pragma unroll
            for (int c = 0; c < 4; ++c) {
                int el = tid + c * 256;          // uint4 index, 1024 total
                uint4 v = srcp[el];
                int n = el >> 2, kk8 = (el & 3) * 8;
                *(uint4*)&Bls[n * 40 + kk8] = v;
            }
        }
        __syncthreads();
        uint4 af[4], bfr[4];
        #pragma unroll
        for (int t = 0; t < 4; ++t)
            af[t] = *(const uint4*)&Als[(t * 16 + c15) * 40 + quad * 8];
        #pragma unroll
        for (int t = 0; t < 4; ++t)
            bfr[t] = *(const uint4*)&Bls[(wv * 64 + t * 16 + c15) * 40 + quad * 8];
        #pragma unroll
        for (int tm = 0; tm < 4; ++tm)
            #pragma unroll
            for (int tn = 0; tn < 4; ++tn)
                acc[tm][tn] = __builtin_amdgcn_mfma_f32_16x16x32_bf16(
                    __builtin_bit_cast(bf16x8, af[tm]),
                    __builtin_bit_cast(bf16x8, bfr[tn]),
                    acc[tm][tn], 0, 0, 0);
    }

    // alpha partials on ORIGINAL channel indexing (heads unchanged by the permute)
    float asv[4], adv[4];
    #pragma unroll
    for (int tn = 0; tn < 4; ++tn) {
        asv[tn] = att_s[wv * 64 + tn * 16 + c15];
        adv[tn] = att_d[wv * 64 + tn * 16 + c15];
    }
    float ps[4][4], pd[4][4];
    #pragma unroll
    for (int tm = 0; tm < 4; ++tm)
        #pragma unroll
        for (int r = 0; r < 4; ++r) {
            float vs = 0.f, vd = 0.f;
            #pragma unroll
            for (int tn = 0; tn < 4; ++tn) {
                float a = acc[tm][tn][r];
                vs += a * asv[tn]; vd += a * adv[tn];
            }
            ps[tm][r] = vs; pd[tm][r] = vd;
        }
    // permuted stores: h1b'[row][wv*64 + c15*4 + tn] -> one uint2 (4 bf16) per (tm,r)
    #pragma unroll
    for (int tm = 0; tm < 4; ++tm) {
        #pragma unroll
        for (int r = 0; r < 4; ++r) {
            int row = row0 + tm * 16 + quad * 4 + r;
            if (row < NNODES) {
                uint2 pk;
                pk.x = (uint_t)f2bf(acc[tm][0][r]) | ((uint_t)f2bf(acc[tm][1][r]) << 16);
                pk.y = (uint_t)f2bf(acc[tm][2][r]) | ((uint_t)f2bf(acc[tm][3][r]) << 16);
                *(uint2*)&h1b[(size_t)row * 256 + wv * 64 + c15 * 4] = pk;
            }
        }
    }
    #pragma unroll
    for (int off = 1; off < 16; off <<= 1)
        #pragma unroll
        for (int tm = 0; tm < 4; ++tm)
            #pragma unroll
            for (int r = 0; r < 4; ++r) {
                ps[tm][r] += __shfl_xor(ps[tm][r], off, 64);
                pd[tm][r] += __shfl_xor(pd[tm][r], off, 64);
            }
    if (c15 == 0) {
        #pragma unroll
        for (int tm = 0; tm < 4; ++tm)
            #pragma unroll
            for (int r = 0; r < 4; ++r) {
                int row = row0 + tm * 16 + quad * 4 + r;
                if (row < NNODES) {
                    as1[row * 4 + wv] = ps[tm][r];
                    ad1[row * 4 + wv] = pd[tm][r];
                }
            }
    }
}

// ------- fused layer-1: TWO nodes per wave, 8-deep reg-shuffle gather -------
__global__ __launch_bounds__(256) void f1_k(const int* __restrict__ cnt,
                                            const int* __restrict__ bkt,
                                            const float* __restrict__ as1,
                                            const float* __restrict__ ad1,
                                            const ushort_t* __restrict__ h1b,
                                            const float* __restrict__ b1p,
                                            const float* __restrict__ W2p,
                                            const float* __restrict__ a2sw,
                                            const float* __restrict__ a2dw,
                                            float* __restrict__ h2,
                                            float* __restrict__ a2s,
                                            float* __restrict__ a2d) {
    int wv = threadIdx.x >> 6;
    int lane = threadIdx.x & 63;
    int half = lane >> 5, l32 = lane & 31;
    int node = blockIdx.x * 8 + wv * 2 + half;
    int h = l32 >> 3;                     // head of this lane's 8 channels
    int deg = min(cnt[node * CPAD], BSLOTS);
    const int* bp = bkt + (size_t)node * BSLOTS;
    float4 advec = *(const float4*)&ad1[(size_t)node * 4];
    __shared__ float wls[4][2][32][4];    // unnormalized exp weights per (edge, head)

    float acc[8] = {};
    float dn0, dn1, dn2, dn3;
    if (deg <= 32) {
        bool act = l32 < deg;
        int s_reg = node;                 // pad: self row (weight 0)
        if (act) s_reg = bp[l32];
        float4 av = *(const float4*)&as1[(size_t)s_reg * 4];
        float e0 = act ? __expf(leaky(av.x + advec.x)) : 0.f;
        float e1 = act ? __expf(leaky(av.y + advec.y)) : 0.f;
        float e2 = act ? __expf(leaky(av.z + advec.z)) : 0.f;
        float e3 = act ? __expf(leaky(av.w + advec.w)) : 0.f;
        *(float4*)&wls[wv][half][l32][0] = make_float4(e0, e1, e2, e3);
        dn0 = e0; dn1 = e1; dn2 = e2; dn3 = e3;
        #pragma unroll
        for (int off = 16; off; off >>= 1) {     // 32-lane reduce, stays in half
            dn0 += __shfl_xor(dn0, off, 64);
            dn1 += __shfl_xor(dn1, off, 64);
            dn2 += __shfl_xor(dn2, off, 64);
            dn3 += __shfl_xor(dn3, off, 64);
        }
        int nb = (deg + 7) & ~7;          // 8-deep batches
        int sbase = half << 5;
        for (int base = 0; base < nb; base += 8) {
            #pragma unroll
            for (int u = 0; u < 8; ++u) {
                int e = base + u;
                int se = __shfl(s_reg, sbase + e, 64);
                float w = wls[wv][half][e][h];
                uint4 v = *(const uint4*)&h1b[(size_t)se * 256 + l32 * 8];
                acc[0] += w * lof(v.x); acc[1] += w * hif(v.x);
                acc[2] += w * lof(v.y); acc[3] += w * hif(v.y);
                acc[4] += w * lof(v.z); acc[5] += w * hif(v.z);
                acc[6] += w * lof(v.w); acc[7] += w * hif(v.w);
            }
        }
    } else {
        // fallback deg 33..96 — rare (P ~ 5e-4 per node)
        dn0 = dn1 = dn2 = dn3 = 0.f;
        for (int j = l32; j < deg; j += 32) {
            int s = bp[j];
            float4 av = *(const float4*)&as1[(size_t)s * 4];
            dn0 += __expf(leaky(av.x + advec.x));
            dn1 += __expf(leaky(av.y + advec.y));
            dn2 += __expf(leaky(av.z + advec.z));
            dn3 += __expf(leaky(av.w + advec.w));
        }
        #pragma unroll
        for (int off = 16; off; off >>= 1) {
            dn0 += __shfl_xor(dn0, off, 64);
            dn1 += __shfl_xor(dn1, off, 64);
            dn2 += __shfl_xor(dn2, off, 64);
            dn3 += __shfl_xor(dn3, off, 64);
        }
        float advh = hsel(advec, h);
        int cmax = deg - 1;
        for (int base = 0; base < deg; base += 8) {
            #pragma unroll
            for (int u = 0; u < 8; ++u) {
                int e = base + u;
                int ce = min(e, cmax);
                int se = bp[ce];
                float ash = as1[(size_t)se * 4 + h];
                float w = (e < deg) ? __expf(leaky(ash + advh)) : 0.f;
                uint4 v = *(const uint4*)&h1b[(size_t)se * 256 + l32 * 8];
                acc[0] += w * lof(v.x); acc[1] += w * hif(v.x);
                acc[2] += w * lof(v.y); acc[3] += w * hif(v.y);
                acc[4] += w * lof(v.z); acc[5] += w * hif(v.z);
                acc[6] += w * lof(v.w); acc[7] += w * hif(v.w);
            }
        }
    }
    float rdh = 1.f / hsel(make_float4(dn0, dn1, dn2, dn3), h);
    #pragma unroll
    for (int c = 0; c < 8; ++c) acc[c] *= rdh;

    // relu(acc + b1p) -> GEMM2 (256 -> 8, permuted rows) -> alpha2 dots
    int k0 = l32 * 8;
    float4 ba = *(const float4*)&b1p[k0];
    float4 bb = *(const float4*)&b1p[k0 + 4];
    float xv[8];
    xv[0] = fmaxf(acc[0] + ba.x, 0.f); xv[1] = fmaxf(acc[1] + ba.y, 0.f);
    xv[2] = fmaxf(acc[2] + ba.z, 0.f); xv[3] = fmaxf(acc[3] + ba.w, 0.f);
    xv[4] = fmaxf(acc[4] + bb.x, 0.f); xv[5] = fmaxf(acc[5] + bb.y, 0.f);
    xv[6] = fmaxf(acc[6] + bb.z, 0.f); xv[7] = fmaxf(acc[7] + bb.w, 0.f);
    float p[8] = {};
    #pragma unroll
    for (int q = 0; q < 8; ++q) {
        const float4* w2p = (const float4*)&W2p[(size_t)(k0 + q) * 8];
        float4 wa = w2p[0], wb = w2p[1];
        p[0] += xv[q] * wa.x; p[1] += xv[q] * wa.y; p[2] += xv[q] * wa.z; p[3] += xv[q] * wa.w;
        p[4] += xv[q] * wb.x; p[5] += xv[q] * wb.y; p[6] += xv[q] * wb.z; p[7] += xv[q] * wb.w;
    }
    #pragma unroll
    for (int off = 16; off; off >>= 1)
        #pragma unroll
        for (int c = 0; c < 8; ++c) p[c] += __shfl_xor(p[c], off, 64);
    if (l32 == 0) {
        *(float4*)&h2[(size_t)node * 8]     = make_float4(p[0], p[1], p[2], p[3]);
        *(float4*)&h2[(size_t)node * 8 + 4] = make_float4(p[4], p[5], p[6], p[7]);
        float vs = 0.f, vd = 0.f;
        #pragma unroll
        for (int c = 0; c < 8; ++c) { vs += p[c] * a2sw[c]; vd += p[c] * a2dw[c]; }
        a2s[node] = vs; a2d[node] = vd;
    }
}

// ------- fused layer-2: TWO nodes per wave, 8-deep dual-chain gather + log_softmax -------
__global__ __launch_bounds__(256) void f2_k(const int* __restrict__ cnt,
                                            const int* __restrict__ bkt,
                                            const float* __restrict__ a2s,
                                            const float* __restrict__ a2d,
                                            const float* __restrict__ h2,
                                            const float* __restrict__ b2,
                                            float* __restrict__ out) {
    int wv = threadIdx.x >> 6;
    int lane = threadIdx.x & 63;
    int half = lane >> 5, l32 = lane & 31;
    int node = blockIdx.x * 8 + wv * 2 + half;
    int deg = min(cnt[node * CPAD], BSLOTS);
    const int* bp = bkt + (size_t)node * BSLOTS;
    float adv = a2d[node];

    float acc_a = 0.f, acc_b = 0.f;
    float den;
    int c = l32 & 7, eg = l32 >> 3;        // 8 edges per pass (2 chains x 4), 8 ch each
    if (deg <= 32) {
        bool act = l32 < deg;
        int s_reg = node;
        if (act) s_reg = bp[l32];
        float ex = act ? __expf(leaky(a2s[s_reg] + adv)) : 0.f;
        den = ex;
        #pragma unroll
        for (int off = 16; off; off >>= 1) den += __shfl_xor(den, off, 64);
        int nb = (deg + 7) & ~7;
        int sbase = half << 5;
        for (int base = 0; base < nb; base += 8) {
            int e1 = base + eg, e2 = base + 4 + eg;
            int se1 = __shfl(s_reg, sbase + e1, 64);
            float w1 = __shfl(ex,    sbase + e1, 64);
            int se2 = __shfl(s_reg, sbase + e2, 64);
            float w2 = __shfl(ex,    sbase + e2, 64);
            acc_a += w1 * h2[(size_t)se1 * 8 + c];
            acc_b += w2 * h2[(size_t)se2 * 8 + c];
        }
    } else {
        den = 0.f;
        for (int j = l32; j < deg; j += 32) {
            int s = bp[j];
            den += __expf(leaky(a2s[s] + adv));
        }
        #pragma unroll
        for (int off = 16; off; off >>= 1) den += __shfl_xor(den, off, 64);
        int cmax = deg - 1;
        for (int base = 0; base < deg; base += 4) {
            int e = base + eg, ce = min(e, cmax);
            int se = bp[ce];
            float w = (e < deg) ? __expf(leaky(a2s[se] + adv)) : 0.f;
            acc_a += w * h2[(size_t)se * 8 + c];
        }
    }
    float acc = acc_a + acc_b;
    acc += __shfl_xor(acc, 8, 64);
    acc += __shfl_xor(acc, 16, 64);
    acc /= den;

    float v = acc + b2[c];
    float mx = v;
    #pragma unroll
    for (int off = 1; off < 8; off <<= 1) mx = fmaxf(mx, __shfl_xor(mx, off, 64));
    float ex2 = __expf(v - mx);
    float ss = ex2;
    #pragma unroll
    for (int off = 1; off < 8; off <<= 1) ss += __shfl_xor(ss, off, 64);
    if (l32 < 8) out[(size_t)node * 8 + c] = v - (mx + __logf(ss));
}

extern "C" void kernel_launch(void* const* d_in, const int* in_sizes, int n_in,
                              void* d_out, int out_size, void* d_ws, size_t ws_size,
                              hipStream_t stream) {
    const float* x    = (const float*)d_in[0];
    const int*   ei   = (const int*)  d_in[1];
    const float* W1   = (const float*)d_in[2];
    const float* a1sw = (const float*)d_in[3];
    const float* a1dw = (const float*)d_in[4];
    const float* b1   = (const float*)d_in[5];
    const float* W2   = (const float*)d_in[6];
    const float* a2sw = (const float*)d_in[7];
    const float* a2dw = (const float*)d_in[8];
    const float* b2   = (const float*)d_in[9];
    float* out = (float*)d_out;

    ushort_t* h1b = (ushort_t*)d_ws;          // 12,800,000 bf16 (permuted channels)
    ushort_t* W1c = h1b + 12800000;           //     65,536 bf16 (chunked W1)
    float* as1  = (float*)(W1c + 65536);      //    200,000 f (16B-aligned)
    float* ad1  = as1 + 200000;               //    200,000 f
    float* h2   = ad1 + 200000;               //    400,000 f
    float* a2s  = h2  + 400000;               //     50,000 f
    float* a2d  = a2s + 50000;                //     50,000 f
    float* b1p  = a2d + 50000;                //        256 f (permuted b1)
    float* W2p  = b1p + 256;                  //      2,048 f (permuted W2)
    int*   cnt  = (int*)(W2p + 2048);         //    800,000 i (64B-strided counters)
    int*   bkt  = cnt + NNODES * CPAD;        //  4,800,000 i (50000 * 96 slots)

    // ---- prep: W1 conv + b1/W2 permute + padded cnt zero ----
    prep_k<<<257, 256, 0, stream>>>(W1, W1c, b1, W2, b1p, W2p, cnt);

    // ---- gemm1 (MFMA bf16, fused alpha1, permuted store) || bucketed CSR ----
    gb_k<<<NTILE + BBLK, 256, 0, stream>>>(x, W1c, a1sw, a1dw, h1b, as1, ad1,
                                           ei, cnt, bkt);

    // ---- fused layer-1 gather + GEMM2 + alpha2 (2 nodes per wave, 8-deep) ----
    f1_k<<<NNODES / 8, 256, 0, stream>>>(cnt, bkt, as1, ad1, h1b, b1p, W2p,
                                         a2sw, a2dw, h2, a2s, a2d);

    // ---- fused layer-2 gather + log_softmax (2 nodes per wave, 8-deep) ----
    f2_k<<<NNODES / 8, 256, 0, stream>>>(cnt, bkt, a2s, a2d, h2, b2, out);
}